// Round 9
// baseline (133.821 us; speedup 1.0000x reference)
//
#include <hip/hip_runtime.h>
#include <stdint.h>

// Problem constants (fixed by reference)
#define NB 32    // batch
#define NC 64    // input channels
#define NH 64
#define NW 64
#define NO 512   // output channels
// xh padded layout: [NB][66 hp][66 wp][64 c], hp/wp 0 and 65 are zeros

typedef __bf16 bf16x8 __attribute__((ext_vector_type(8)));
typedef short  s16x8  __attribute__((ext_vector_type(8)));
typedef float  f32x4  __attribute__((ext_vector_type(4)));

__device__ __forceinline__ uint16_t f2bf(float f) {
  uint32_t u = __builtin_bit_cast(uint32_t, f);
  u += 0x7fffu + ((u >> 16) & 1u);   // round-to-nearest-even
  return (uint16_t)(u >> 16);
}

// async global->LDS, 16B per lane. LDS dest = wave-uniform base + lane*16.
__device__ __forceinline__ void gld16(const uint16_t* g, uint16_t* l) {
  __builtin_amdgcn_global_load_lds(
      (const __attribute__((address_space(1))) void*)(g),
      (__attribute__((address_space(3))) void*)(l), 16, 0, 0);
}

// ---------------- kernel 1: build effective weights (pre-swizzled) -------
// W_eff[o][c][p] = sum_s coef[o,s]*dict[idx[o,s]][c][p], p = kh*3+kw.
//   Wl[((p*NO + o)*8 + ((c>>3) ^ (o&7)))*8 + (c&7)]
__global__ void k_build_w(const float* __restrict__ dict,
                          const float* __restrict__ coef,
                          const int*   __restrict__ idx,
                          uint16_t*    __restrict__ Wl) {
  __shared__ float tmp[576];
  const int o = blockIdx.x;
  const int t = threadIdx.x;      // 0..575
  float v = 0.f;
#pragma unroll
  for (int s = 0; s < 4; ++s)
    v += coef[o * 4 + s] * dict[idx[o * 4 + s] * 576 + t];
  tmp[t] = v;
  __syncthreads();
  const int c = t & 63, p = t >> 6;   // 576 = 9*64
  const int sl = ((p * NO + o) * 8 + ((c >> 3) ^ (o & 7))) * 8 + (c & 7);
  Wl[sl] = f2bf(tmp[c * 9 + p]);
}

// ---------------- kernel 2: x NCHW fp32 -> h/w-padded swizzled bf16 ------
// xh[b][hp][wp][c]; hp,wp in [0,66), borders zero. Within a row, 16B chunk
// (c>>3) of padded col wp stored at chunk slot ((c>>3) ^ (wp&7)).
__global__ void k_nhwc(const float* __restrict__ x, uint16_t* __restrict__ xh) {
  const int bh = blockIdx.x;            // b*66 + hp
  const int b = bh / 66, hp = bh % 66;
  const int t = threadIdx.x;            // 256
  uint16_t* row = xh + (size_t)(b * 66 + hp) * 4224;   // 66*64 elems
  int4* r4 = reinterpret_cast<int4*>(row);             // 528 int4
  if (hp == 0 || hp == 65) {            // zero h-pad rows
    for (int j = t; j < 528; j += 256) r4[j] = int4{0, 0, 0, 0};
    return;
  }
  __shared__ float tile[64][65];
  const int h = hp - 1;
  const int w = t & 63;
#pragma unroll
  for (int c = (t >> 6); c < 64; c += 4)
    tile[c][w] = x[((size_t)(b * NC + c) * NH + h) * NW + w];
  __syncthreads();
  if (t < 16)                           // zero w-pad cols wp=0 and wp=65
    r4[(t >> 3) * 520 + (t & 7)] = int4{0, 0, 0, 0};
#pragma unroll
  for (int i = 0; i < 2; ++i) {
    const int s = t + i * 256;          // 512 slots: w2 (0..63), cb (0..7)
    const int w2 = s >> 3, cb = s & 7;
    const int wp = w2 + 1;              // padded col
    uint32_t d[4];
#pragma unroll
    for (int j = 0; j < 4; ++j) {
      const uint32_t lo = f2bf(tile[cb * 8 + 2 * j][w2]);
      const uint32_t hi = f2bf(tile[cb * 8 + 2 * j + 1][w2]);
      d[j] = lo | (hi << 16);
    }
    r4[wp * 8 + (cb ^ (wp & 7))] =
        int4{(int)d[0], (int)d[1], (int)d[2], (int)d[3]};
  }
}

// ---------------- kernel 3: 256x256-tile 1-tap-per-K-step GEMM conv ------
// M=512(o) x N=131072(pix) x K=576. BK=64 = one tap. 1024 blocks, 512 thr.
// Wave = 128 o x 64 pix (1 h-row), acc[4][8] f32x4 (pix rows via operand
// swap -> f32x4 w-contiguous nt stores).
// LDS = 4 rotating 32 KB slots (A(k):slot 2k%4, B(k):slot (2k+1)%4).
// Steady K-step: barrier / issue A(k+1)+B(k+1) (8 gld16) / vmcnt(8)+barrier
// (counted: step-k panels landed, next step's 8 loads STAY IN FLIGHT) /
// 24 ds_read + 64 MFMA with setprio. vmcnt never drains to 0 mid-loop.
__global__ __launch_bounds__(512, 2) void k_conv(
    const uint16_t* __restrict__ xh,   // [NB][66][66][64] bf16, pre-swizzled
    const uint16_t* __restrict__ Wl,   // [9][512][64] bf16, pre-swizzled
    const float*    __restrict__ bias,
    float*          __restrict__ out) {
  __shared__ __align__(16) uint16_t lds[4 * 16384];   // 128 KB

  const int t = threadIdx.x;
  const int lane = t & 63;
  const int wid  = t >> 6;      // 0..7
  // XCD-chunked: XCD j gets contiguous s-range (64 pix-tiles = 4 b's)
  const int flat = blockIdx.x;                 // 1024 blocks
  const int s    = (flat & 7) * 128 + (flat >> 3);
  const int mt   = s & 1;                      // o-half
  const int pt   = s >> 1;                     // pixel tile: b*16 + h-quad
  const int O0 = mt * 256;
  const int b  = pt >> 4;
  const int h0 = (pt & 15) * 4;

  const int wm  = wid & 1;      // o sub (128 each)
  const int wn  = wid >> 1;     // h-row 0..3
  const int l15 = lane & 15;
  const int lg  = lane >> 4;

  auto stageA = [&](int k) {
    uint16_t* dst = lds + ((2 * k) & 3) * 16384;
    const uint16_t* src = Wl + ((size_t)k * NO + O0) * 64;
#pragma unroll
    for (int j = 0; j < 4; ++j) {
      const int ch = wid * 4 + j;              // 0..31 x 1KB
      gld16(src + ch * 512 + lane * 8, dst + ch * 512);
    }
  };
  auto stageB = [&](int k) {
    uint16_t* dst = lds + ((2 * k + 1) & 3) * 16384;
    const int dh = k / 3, dwp = k % 3;         // hp offset dh, wp base dwp
#pragma unroll
    for (int j = 0; j < 4; ++j) {
      const int ch = wid * 4 + j;              // r = ch>>3, w-oct = ch&7
      const int r = ch >> 3, oc = ch & 7;
      const uint16_t* src =
          xh + ((size_t)(b * 66) + h0 + r + dh) * 4224 + (dwp + oc * 8) * 64;
      gld16(src + lane * 8, dst + ch * 512);
    }
  };

  float bvv[8];
#pragma unroll
  for (int ob = 0; ob < 8; ++ob)
    bvv[ob] = bias[O0 + wm * 128 + ob * 16 + l15];

  f32x4 acc[4][8];
#pragma unroll
  for (int pb = 0; pb < 4; ++pb)
#pragma unroll
    for (int ob = 0; ob < 8; ++ob)
      acc[pb][ob] = (f32x4){0.f, 0.f, 0.f, 0.f};

  stageA(0);
  stageB(0);

#pragma unroll
  for (int k = 0; k < 9; ++k) {
    if (k > 0)
      asm volatile("s_barrier" ::: "memory");  // slots of k-1 now free
    if (k < 8) { stageA(k + 1); stageB(k + 1); }
    if (k < 8)
      asm volatile("s_waitcnt vmcnt(8)\n\ts_barrier" ::: "memory");
    else
      asm volatile("s_waitcnt vmcnt(0)\n\ts_barrier" ::: "memory");

    const uint16_t* As = lds + ((2 * k) & 3) * 16384;
    const uint16_t* Bs = lds + ((2 * k + 1) & 3) * 16384;
    const int dwp = k % 3;

#pragma unroll
    for (int q = 0; q < 2; ++q) {
      const int cbA = (q * 4 + lg) ^ (l15 & 7);
      const int cbB = (q * 4 + lg) ^ ((l15 + dwp) & 7);
      bf16x8 af[8], braw[4];
#pragma unroll
      for (int ob = 0; ob < 8; ++ob)
        af[ob] = __builtin_bit_cast(bf16x8,
            *reinterpret_cast<const s16x8*>(
                As + (wm * 128 + ob * 16 + l15) * 64 + cbA * 8));
#pragma unroll
      for (int pb = 0; pb < 4; ++pb)
        braw[pb] = __builtin_bit_cast(bf16x8,
            *reinterpret_cast<const s16x8*>(
                Bs + (wn * 64 + pb * 16 + l15) * 64 + cbB * 8));
      __builtin_amdgcn_s_setprio(1);
#pragma unroll
      for (int pb = 0; pb < 4; ++pb)
#pragma unroll
        for (int ob = 0; ob < 8; ++ob)
          acc[pb][ob] = __builtin_amdgcn_mfma_f32_16x16x32_bf16(
              braw[pb], af[ob], acc[pb][ob], 0, 0, 0);
      __builtin_amdgcn_s_setprio(0);
    }
  }

  // ---- epilogue: direct f32x4 nt stores (layout verified R7/R8) ----
  const int h = h0 + wn;
#pragma unroll
  for (int pb = 0; pb < 4; ++pb) {
#pragma unroll
    for (int ob = 0; ob < 8; ++ob) {
      const int o = O0 + wm * 128 + ob * 16 + l15;
      f32x4 v = acc[pb][ob];
      const float bv = bvv[ob];
      v[0] += bv; v[1] += bv; v[2] += bv; v[3] += bv;
      float* dst = out + ((size_t)(b * NO + o) * NH + h) * NW +
                   pb * 16 + lg * 4;
      __builtin_nontemporal_store(v, reinterpret_cast<f32x4*>(dst));
    }
  }
}

extern "C" void kernel_launch(void* const* d_in, const int* in_sizes, int n_in,
                              void* d_out, int out_size, void* d_ws, size_t ws_size,
                              hipStream_t stream) {
  const float* x    = (const float*)d_in[0];
  const float* dict = (const float*)d_in[1];
  const float* coef = (const float*)d_in[2];
  const float* bias = (const float*)d_in[3];
  const int*   idx  = (const int*)d_in[4];
  float* out = (float*)d_out;

  // workspace: xh padded/swizzled = 32*66*66*64*2 B = 17.84 MB at 0;
  //            Wl swizzled 576 KiB at +18 MiB
  uint16_t* xh = (uint16_t*)d_ws;
  uint16_t* Wl = (uint16_t*)((char*)d_ws + (18u << 20));

  hipLaunchKernelGGL(k_build_w, dim3(NO), dim3(576), 0, stream, dict, coef, idx, Wl);
  hipLaunchKernelGGL(k_nhwc, dim3(NB * 66), dim3(256), 0, stream, x, xh);
  hipLaunchKernelGGL(k_conv, dim3(1024), dim3(512), 0, stream, xh, Wl, bias, out);
}